// Round 2
// baseline (389.807 us; speedup 1.0000x reference)
//
#include <hip/hip_runtime.h>
#include <hip/hip_bf16.h>
#include <hip/hip_cooperative_groups.h>

namespace cg = cooperative_groups;

// Problem constants
#define B_     16384
#define NS_    26
#define ND_    13
#define V_     100000
#define H_     400
#define NP     448          // padded N and K for every DNN layer
#define MT     32           // rows per fused block; 512 blocks = exactly 2/CU (coop co-resident)
#define ASTR   456          // act LDS row stride in BYTES (448 + 8; /4=114≡18 mod 32 -> 16-bank spread)
#define WCHB   (448 * 64)   // bytes per weight k-chunk [448 n][64 k] fp8
#define WQTR   (112 * 64)   // per-wave quarter of a chunk (7168 B)

// LDS layout (bytes) — 72192 total => 2 blocks/CU (144384 <= 160K)
// prep phase aliases smem[0 .. 16640) as a float[64][65] tile (barrier-separated
// from act/wbuf use; fmv/dotv live above 71936 so never alias the tile).
#define ACT_OFF   0
#define WBUF_OFF  (MT * ASTR)                  // 14592
#define FMV_OFF   (WBUF_OFF + 2 * WCHB)        // 71936
#define DOT_OFF   (FMV_OFF + 128)              // 72064
#define LDSB      (DOT_OFF + 128)              // 72192

// s_waitcnt immediates: vmcnt | expcnt<<4 | lgkmcnt<<8 (gfx9 encoding)
#define WAIT_VM7  0x0F77    // vmcnt(7)  lgkm(15) exp(7)
#define WAIT_VM0  0x0F70    // vmcnt(0)  lgkm(15) exp(7)

// Scaling (all powers of 2, algebra exact in fp32 epilogues):
//  act0 sparse cols x 2^12, dense cols x 2^6; weights x 2^12
//  (layer0 dense-row weights x 2^18 to unify); acc0 = 2^24 * true
//  A1 = 2^21, A2 = 2^31 -> f0 = 2^-3, f1 = 2^-2, final g = 2^-43.
#define SC_A1   2097152.0f
#define SC_A2   2147483648.0f
#define SC_F0   0.125f
#define SC_F1   0.25f
#define SC_G    1.1368683772161603e-13f

typedef float f32x4 __attribute__((ext_vector_type(4)));

__device__ __forceinline__ unsigned char f2fp8(float v) {
  int pk = __builtin_amdgcn_cvt_pk_fp8_f32(v, v, 0, false);
  return (unsigned char)(pk & 0xff);
}

// ---------------------------------------------------------------------------
// Per-wave weight staging: wave w DMAs ONLY its own n-range [w*112, w*112+112)
// into its private quarter of the chunk buffer -> no cross-wave wbuf deps ->
// no barriers in the K-loop. 16B granules XOR-swizzled on the *source* side
// (slot s holds granule g = (s&3) ^ ((n_local>>1)&3)) so b64 reads spread
// across ~16+ banks instead of 8 (row stride 64B is pathological unswizzled).
// ---------------------------------------------------------------------------
__device__ __forceinline__ void stage_w_chunk(
    const unsigned char* __restrict__ Wt, int kt, unsigned char* wb,
    int wave, int lane) {
  const unsigned char* wrow = Wt + (size_t)(wave * 112) * NP + kt * 64;
  unsigned char* lbase = wb + wave * WQTR;
#pragma unroll
  for (int i = 0; i < 7; ++i) {
    int s = i * 64 + lane;
    int nl = s >> 2;
    int g = (s & 3) ^ ((nl >> 1) & 3);
    const unsigned char* gp = wrow + (size_t)nl * NP + g * 16;
    unsigned char* lp = lbase + (size_t)(i * 64) * 16;   // wave-uniform + lane*16
    __builtin_amdgcn_global_load_lds(
        (const __attribute__((address_space(1))) unsigned int*)gp,
        (__attribute__((address_space(3))) unsigned int*)lp, 16, 0, 0);
  }
}

// ---------------------------------------------------------------------------
// fused_all (cooperative, single dispatch):
//  phase 0 (blocks 0..147): weight transpose/quantize fp32->fp8 + bias prep,
//           overlapped with every block's gather phase; grid.sync() after.
//  phase 1: gather emb2 (float4, 8 thr/row, feature-parity split) -> fp8 act
//           in LDS; FM in fp32 with shfl combine.
//  phase 2: 3 fp8 MFMA layers, act in place; weight chunks double-buffered,
//           K-loop barrier-free with per-wave s_waitcnt vmcnt gating.
//  phase 3: layer-2 epilogue fuses h2 . W_out; single out write per row.
// ---------------------------------------------------------------------------
__global__ __launch_bounds__(256, 2) void fused_all(
    const int* __restrict__ Xs, const float* __restrict__ Xd,
    const float* __restrict__ emb1, const float* __restrict__ emb2,
    const float* __restrict__ linw, const float* __restrict__ bias,
    const float* __restrict__ W0, const float* __restrict__ b0,
    const float* __restrict__ W1, const float* __restrict__ b1,
    const float* __restrict__ W2, const float* __restrict__ b2,
    const float* __restrict__ Wout,
    unsigned char* __restrict__ W0t, unsigned char* __restrict__ W1t,
    unsigned char* __restrict__ W2t,
    float* __restrict__ b0p, float* __restrict__ b1p,
    float* __restrict__ b2p, float* __restrict__ woutp,
    float* __restrict__ out) {
  extern __shared__ char smem[];
  unsigned char* act  = (unsigned char*)(smem + ACT_OFF);   // [32][456] fp8
  unsigned char* wbuf = (unsigned char*)(smem + WBUF_OFF);  // 2 x [4 waves][112][64]
  float* fmv  = (float*)(smem + FMV_OFF);                   // [32]
  float* dotv = (float*)(smem + DOT_OFF);                   // [32]

  const int tid  = threadIdx.x;
  const int wave = tid >> 6;
  const int lane = tid & 63;
  const int quad = lane >> 4;
  const int l16  = lane & 15;
  const int blk  = blockIdx.x;
  const int r0   = blk * MT;

  // ---- phase 0: weight prep, spread over blocks 0..147 (tile aliases smem) --
  if (blk < 147) {
    const int layer = blk / 49;
    const int t = blk - layer * 49;
    const int k0 = (t / 7) * 64, n0 = (t - (t / 7) * 7) * 64;
    const float* W = (layer == 0) ? W0 : (layer == 1) ? W1 : W2;
    unsigned char* Wt = (layer == 0) ? W0t : (layer == 1) ? W1t : W2t;
    const int Kdim = (layer == 0) ? 429 : 400;
    float (*tile)[65] = (float (*)[65])smem;   // 16640 B, barrier-separated alias
#pragma unroll
    for (int p = 0; p < 16; ++p) {
      int kk = p * 4 + (tid >> 6);
      int k = k0 + kk;
      int n = n0 + (tid & 63);
      float v = (k < Kdim && n < H_) ? W[k * H_ + n] : 0.f;
      tile[kk][tid & 63] = v;
    }
    __syncthreads();
#pragma unroll
    for (int p = 0; p < 4; ++p) {
      int nn = p * 16 + (tid >> 4);
      int n = n0 + nn;
      int k4 = (tid & 15) * 4;
      float sc[4];
#pragma unroll
      for (int i = 0; i < 4; ++i) {
        int kabs = k0 + k4 + i;
        sc[i] = (layer == 0 && kabs >= 416) ? 262144.0f : 4096.0f;
      }
      float v0 = tile[k4 + 0][nn] * sc[0];
      float v1 = tile[k4 + 1][nn] * sc[1];
      float v2 = tile[k4 + 2][nn] * sc[2];
      float v3 = tile[k4 + 3][nn] * sc[3];
      int w = __builtin_amdgcn_cvt_pk_fp8_f32(v0, v1, 0, false);
      w = __builtin_amdgcn_cvt_pk_fp8_f32(v2, v3, w, true);
      *(unsigned int*)(Wt + (size_t)n * NP + k0 + k4) = (unsigned int)w;
    }
  } else if (blk == 147) {
#pragma unroll
    for (int it = 0; it < 7; ++it) {
      int j = it * 256 + tid;
      if (j < NP)              b0p[j]          = (j < H_) ? b0[j] * SC_A1 : 0.f;
      else if (j < 2 * NP)     b1p[j - NP]     = (j - NP < H_) ? b1[j - NP] * SC_A2 : 0.f;
      else if (j < 3 * NP)     b2p[j - 2*NP]   = (j - 2*NP < H_) ? b2[j - 2*NP] : 0.f;
      else if (j < 4 * NP)     woutp[j - 3*NP] = (j - 3*NP < H_) ? Wout[j - 3*NP] : 0.f;
    }
  }
  if (blk <= 147) __threadfence();  // publish W*t / b*p device-wide before sync
  __syncthreads();                  // tile alias dead before act writes begin

  // ---- phase 1: FM + act build. 8 rows/wave, 8 thr/row:
  //      t4 = dim quarter (float4), fh = feature parity (13 gathers/lane) ----
  {
    if (tid < MT) dotv[tid] = 0.f;
    const int r   = lane >> 3;
    const int t8  = lane & 7;
    const int t4  = lane & 3;
    const int fh  = (lane >> 2) & 1;
    const int row = wave * 8 + r;
    const int gr  = r0 + row;
    const int* xs = Xs + gr * NS_;

    f32x4 sum = {0.f, 0.f, 0.f, 0.f}, sq = {0.f, 0.f, 0.f, 0.f};
#pragma unroll
    for (int f = fh; f < NS_; f += 2) {
      int idx = xs[f];
      f32x4 v = *(const f32x4*)(emb2 + ((size_t)f * V_ + idx) * 16 + t4 * 4);
      sum += v;
      sq  += v * v;
      int pk = __builtin_amdgcn_cvt_pk_fp8_f32(v[0] * 4096.f, v[1] * 4096.f, 0, false);
      pk = __builtin_amdgcn_cvt_pk_fp8_f32(v[2] * 4096.f, v[3] * 4096.f, pk, true);
      *(unsigned int*)(act + row * ASTR + f * 16 + t4 * 4) = (unsigned int)pk;
    }

    float lin = 0.f;
    for (int f = t8; f < NS_; f += 8)
      lin += emb1[(size_t)f * V_ + xs[f]];

    for (int e = 416 + t8; e < NP; e += 8) act[row * ASTR + e] = 0;
    for (int e = t8; e < ND_; e += 8) {
      float xd = Xd[gr * ND_ + e];
      lin += xd * linw[e];
      act[row * ASTR + 416 + e] = f2fp8(xd * 64.f);
    }

    // combine the two feature-parity halves BEFORE squaring (sum must be total)
    f32x4 sumo, sqo;
#pragma unroll
    for (int i = 0; i < 4; ++i) {
      sumo[i] = __shfl_xor(sum[i], 4, 64);
      sqo[i]  = __shfl_xor(sq[i], 4, 64);
    }
    f32x4 st = sum + sumo;
    f32x4 c4 = st * st - (sq + sqo);
    float fm = (fh == 0) ? 0.5f * (c4[0] + c4[1] + c4[2] + c4[3]) : 0.f;
    fm += lin;
    fm += __shfl_xor(fm, 1, 64);
    fm += __shfl_xor(fm, 2, 64);
    fm += __shfl_xor(fm, 4, 64);
    if (t8 == 0) fmv[row] = fm + bias[0];
  }

  // all prep writes device-visible + all blocks' act built
  cg::this_grid().sync();

  const unsigned char* Wl[3] = {W0t, W1t, W2t};

  // kick off layer-0 chunk-0 DMA (weights now valid)
  stage_w_chunk(W0t, 0, wbuf, wave, lane);

  for (int layer = 0; layer < 3; ++layer) {
    const unsigned char* Wt = Wl[layer];
    const unsigned char* wq = wbuf + wave * WQTR;   // this wave's quarter
    f32x4 acc[2][7] = {};

    // barrier-free K-loop: double-buffered chunks, per-wave vmcnt gating
    for (int kt = 0; kt < 7; ++kt) {
      if (kt < 6) {
        stage_w_chunk(Wt, kt + 1, wbuf + ((kt + 1) & 1) * WCHB, wave, lane);
        __builtin_amdgcn_s_waitcnt(WAIT_VM7);  // chunk kt resident; kt+1 in flight
      } else {
        __builtin_amdgcn_s_waitcnt(WAIT_VM0);  // last chunk of layer
      }
      __builtin_amdgcn_sched_barrier(0);       // keep ds_reads below the wait
      const unsigned char* wb = wq + (kt & 1) * WCHB;

#pragma unroll
      for (int h = 0; h < 2; ++h) {
        long long av[2];
#pragma unroll
        for (int mt = 0; mt < 2; ++mt)
          av[mt] = *(const long long*)(act + (mt * 16 + l16) * ASTR + kt * 64 + h * 32 + quad * 8);
#pragma unroll
        for (int nt = 0; nt < 7; ++nt) {
          int nl = nt * 16 + l16;
          int sw = (2 * h + (quad >> 1)) ^ ((nl >> 1) & 3);
          long long bv = *(const long long*)(wb + nl * 64 + sw * 16 + (quad & 1) * 8);
#pragma unroll
          for (int mt = 0; mt < 2; ++mt)
            acc[mt][nt] = __builtin_amdgcn_mfma_f32_16x16x32_fp8_fp8(av[mt], bv, acc[mt][nt], 0, 0, 0);
        }
      }
    }

    // prefetch next layer's chunk 0 before the barrier (drained there; resident
    // for kt=0 of the next layer)
    if (layer < 2) stage_w_chunk(Wl[layer + 1], 0, wbuf, wave, lane);

    __syncthreads();  // all waves done reading act for this layer

    if (layer < 2) {
      const float fs = (layer == 0) ? SC_F0 : SC_F1;
      const float* bl = (layer == 0) ? b0p : b1p;
#pragma unroll
      for (int nt = 0; nt < 7; ++nt) {
        int col = wave * 112 + nt * 16 + l16;
        float bz = bl[col];
#pragma unroll
        for (int mt = 0; mt < 2; ++mt) {
#pragma unroll
          for (int r = 0; r < 4; ++r) {
            float v = acc[mt][nt][r] * fs + bz;
            v = v > 0.f ? v : 0.f;
            act[(mt * 16 + quad * 4 + r) * ASTR + col] = f2fp8(v);
          }
        }
      }
    } else {
      float wsum[2][4] = {};
#pragma unroll
      for (int nt = 0; nt < 7; ++nt) {
        int col = wave * 112 + nt * 16 + l16;
        float bz = b2p[col];
        float wv = woutp[col];
#pragma unroll
        for (int mt = 0; mt < 2; ++mt) {
#pragma unroll
          for (int r = 0; r < 4; ++r) {
            float v = acc[mt][nt][r] * SC_G + bz;
            v = v > 0.f ? v : 0.f;
            wsum[mt][r] += v * wv;
          }
        }
      }
#pragma unroll
      for (int mt = 0; mt < 2; ++mt) {
#pragma unroll
        for (int r = 0; r < 4; ++r) {
          float s = wsum[mt][r];
          s += __shfl_xor(s, 1, 64);
          s += __shfl_xor(s, 2, 64);
          s += __shfl_xor(s, 4, 64);
          s += __shfl_xor(s, 8, 64);
          if (l16 == 0) atomicAdd(&dotv[mt * 16 + quad * 4 + r], s);
        }
      }
    }
    __syncthreads();  // epilogue writes visible before next layer / final read
  }

  if (tid < MT) out[r0 + tid] = fmv[tid] + dotv[tid];
}

// ---------------------------------------------------------------------------
extern "C" void kernel_launch(void* const* d_in, const int* in_sizes, int n_in,
                              void* d_out, int out_size, void* d_ws, size_t ws_size,
                              hipStream_t stream) {
  const int*   Xs   = (const int*)d_in[0];
  const float* Xd   = (const float*)d_in[1];
  const float* emb1 = (const float*)d_in[2];
  const float* emb2 = (const float*)d_in[3];
  const float* linw = (const float*)d_in[4];
  const float* bias = (const float*)d_in[5];
  const float* W0   = (const float*)d_in[6];
  const float* b0   = (const float*)d_in[7];
  const float* W1   = (const float*)d_in[8];
  const float* b1   = (const float*)d_in[9];
  const float* W2   = (const float*)d_in[10];
  const float* b2   = (const float*)d_in[11];
  const float* Wout = (const float*)d_in[12];
  float* out = (float*)d_out;

  char* ws = (char*)d_ws;
  const size_t WSZ = (size_t)NP * NP;   // 200704 bytes per fp8 weight
  unsigned char* W0t = (unsigned char*)(ws);
  unsigned char* W1t = (unsigned char*)(ws + WSZ);
  unsigned char* W2t = (unsigned char*)(ws + 2 * WSZ);
  float* b0p   = (float*)(ws + 3 * WSZ);
  float* b1p   = (float*)(ws + 3 * WSZ + 1792);
  float* b2p   = (float*)(ws + 3 * WSZ + 2 * 1792);
  float* woutp = (float*)(ws + 3 * WSZ + 3 * 1792);

  (void)hipFuncSetAttribute((const void*)fused_all,
                            hipFuncAttributeMaxDynamicSharedMemorySize, LDSB);

  void* args[] = {&Xs, &Xd, &emb1, &emb2, &linw, &bias,
                  &W0, &b0, &W1, &b1, &W2, &b2, &Wout,
                  &W0t, &W1t, &W2t, &b0p, &b1p, &b2p, &woutp, &out};
  (void)hipLaunchCooperativeKernel((const void*)fused_all, dim3(B_ / MT),
                                   dim3(256), args, LDSB, stream);
}

// Round 3
// 270.519 us; speedup vs baseline: 1.4410x; 1.4410x over previous
//
#include <hip/hip_runtime.h>
#include <hip/hip_bf16.h>

// Problem constants
#define B_     16384
#define NS_    26
#define ND_    13
#define V_     100000
#define H_     400
#define NP     448          // padded N and K for every DNN layer
#define MT     64           // rows per GEMM block
#define ASTR   456          // act LDS row stride BYTES (448+8; /4=114≡18 mod 32 -> 16-bank spread)
#define WCHB   (448 * 64)   // bytes per weight k-chunk [448 n][64 k] fp8
#define WQTR   (112 * 64)   // per-wave quarter of a chunk (7168 B)

// GEMM kernel LDS layout (bytes)
#define ACT_OFF   0
#define WBUF_OFF  (MT * ASTR)                  // 29184
#define DOT_OFF   (WBUF_OFF + 2 * WCHB)        // 86528
#define LDSB      (DOT_OFF + 256)              // 86784

// gather_prep LDS: float[64][65] transpose tile
#define PREP_LDS  16640

// s_waitcnt immediates: vmcnt | expcnt<<4 | lgkmcnt<<8 (gfx9 encoding)
#define WAIT_VM7  0x0F77    // vmcnt(7)  lgkm(15) exp(7)
#define WAIT_VM0  0x0F70    // vmcnt(0)  lgkm(15) exp(7)

// Scaling (all powers of 2, algebra exact in fp32 epilogues):
//  act0 sparse cols x 2^12, dense cols x 2^6; weights x 2^12
//  (layer0 dense-row weights x 2^18 to unify); acc0 = 2^24 * true
//  A1 = 2^21, A2 = 2^31 -> f0 = 2^-3, f1 = 2^-2, final g = 2^-43.
#define SC_A1   2097152.0f
#define SC_A2   2147483648.0f
#define SC_F0   0.125f
#define SC_F1   0.25f
#define SC_G    1.1368683772161603e-13f

typedef float f32x4 __attribute__((ext_vector_type(4)));

__device__ __forceinline__ unsigned char f2fp8(float v) {
  int pk = __builtin_amdgcn_cvt_pk_fp8_f32(v, v, 0, false);
  return (unsigned char)(pk & 0xff);
}

// ---------------------------------------------------------------------------
// gather_prep: blocks [0,147): weight transpose/quantize fp32->fp8 (validated
// prep_w body). Block 147: bias/Wout prep. Blocks [148, 148+2048): emb gather
// at 32 thr/row, 8 rows/block -> fp8 act rows + FM scalar to workspace.
// No MFMA, no act LDS, low VGPR -> 8 blocks/CU = 32 waves/CU for max MLP.
// ---------------------------------------------------------------------------
__global__ __launch_bounds__(256, 8) void gather_prep(
    const int* __restrict__ Xs, const float* __restrict__ Xd,
    const float* __restrict__ emb1, const float* __restrict__ emb2,
    const float* __restrict__ linw, const float* __restrict__ bias,
    const float* __restrict__ W0, const float* __restrict__ b0,
    const float* __restrict__ W1, const float* __restrict__ b1,
    const float* __restrict__ W2, const float* __restrict__ b2,
    const float* __restrict__ Wout,
    unsigned char* __restrict__ W0t, unsigned char* __restrict__ W1t,
    unsigned char* __restrict__ W2t,
    float* __restrict__ b0p, float* __restrict__ b1p,
    float* __restrict__ b2p, float* __restrict__ woutp,
    unsigned char* __restrict__ actw, float* __restrict__ fmw) {
  extern __shared__ char smem[];
  const int blk = blockIdx.x;
  const int tid = threadIdx.x;

  if (blk < 147) {  // ---- weight tile prep (unchanged, validated) ----
    const int layer = blk / 49;
    const int t = blk - layer * 49;
    const int k0 = (t / 7) * 64, n0 = (t - (t / 7) * 7) * 64;
    const float* W = (layer == 0) ? W0 : (layer == 1) ? W1 : W2;
    unsigned char* Wt = (layer == 0) ? W0t : (layer == 1) ? W1t : W2t;
    const int Kdim = (layer == 0) ? 429 : 400;
    float (*tile)[65] = (float (*)[65])smem;
#pragma unroll
    for (int p = 0; p < 16; ++p) {
      int kk = p * 4 + (tid >> 6);
      int k = k0 + kk;
      int n = n0 + (tid & 63);
      float v = (k < Kdim && n < H_) ? W[k * H_ + n] : 0.f;
      tile[kk][tid & 63] = v;
    }
    __syncthreads();
#pragma unroll
    for (int p = 0; p < 4; ++p) {
      int nn = p * 16 + (tid >> 4);
      int n = n0 + nn;
      int k4 = (tid & 15) * 4;
      float sc[4];
#pragma unroll
      for (int i = 0; i < 4; ++i) {
        int kabs = k0 + k4 + i;
        sc[i] = (layer == 0 && kabs >= 416) ? 262144.0f : 4096.0f;
      }
      float v0 = tile[k4 + 0][nn] * sc[0];
      float v1 = tile[k4 + 1][nn] * sc[1];
      float v2 = tile[k4 + 2][nn] * sc[2];
      float v3 = tile[k4 + 3][nn] * sc[3];
      int w = __builtin_amdgcn_cvt_pk_fp8_f32(v0, v1, 0, false);
      w = __builtin_amdgcn_cvt_pk_fp8_f32(v2, v3, w, true);
      *(unsigned int*)(Wt + (size_t)n * NP + k0 + k4) = (unsigned int)w;
    }
    return;
  }
  if (blk == 147) {  // ---- bias / Wout prep ----
#pragma unroll
    for (int it = 0; it < 7; ++it) {
      int j = it * 256 + tid;
      if (j < NP)              b0p[j]          = (j < H_) ? b0[j] * SC_A1 : 0.f;
      else if (j < 2 * NP)     b1p[j - NP]     = (j - NP < H_) ? b1[j - NP] * SC_A2 : 0.f;
      else if (j < 3 * NP)     b2p[j - 2*NP]   = (j - 2*NP < H_) ? b2[j - 2*NP] : 0.f;
      else if (j < 4 * NP)     woutp[j - 3*NP] = (j - 3*NP < H_) ? Wout[j - 3*NP] : 0.f;
    }
    return;
  }

  // ---- gather: 32 thr/row. t4 = dim quarter (float4), fo = feature group ----
  const int g   = blk - 148;        // 0..2047
  const int rh  = tid >> 5;         // 0..7 rows per block
  const int t   = tid & 31;
  const int t4  = t & 3;
  const int fo  = t >> 2;           // 0..7
  const int row = g * 8 + rh;
  const int* xs = Xs + row * NS_;
  unsigned char* arow = actw + (size_t)row * NP;

  f32x4 sum = {0.f, 0.f, 0.f, 0.f}, sq = {0.f, 0.f, 0.f, 0.f};
#pragma unroll
  for (int j = 0; j < 4; ++j) {
    int f = fo + j * 8;
    if (f < NS_) {
      int idx = xs[f];
      f32x4 v = *(const f32x4*)(emb2 + ((size_t)f * V_ + idx) * 16 + t4 * 4);
      sum += v;
      sq  += v * v;
      int pk = __builtin_amdgcn_cvt_pk_fp8_f32(v[0] * 4096.f, v[1] * 4096.f, 0, false);
      pk = __builtin_amdgcn_cvt_pk_fp8_f32(v[2] * 4096.f, v[3] * 4096.f, pk, true);
      *(unsigned int*)(arow + f * 16 + t4 * 4) = (unsigned int)pk;
    }
  }

  // per-lane extras: emb1 (t<26), dense cols 416..447 (t<13 data, rest zero)
  float lin = 0.f;
  if (t < NS_) lin = emb1[(size_t)t * V_ + xs[t]];
  unsigned char dv = 0;
  if (t < ND_) {
    float xd = Xd[row * ND_ + t];
    lin += xd * linw[t];
    dv = f2fp8(xd * 64.f);
  }
  arow[416 + t] = dv;   // 32 consecutive bytes: 13 dense + 19 zero pad

  // combine feature groups BEFORE squaring (sum must be total over 26 feats)
#pragma unroll
  for (int m = 4; m <= 16; m <<= 1) {
#pragma unroll
    for (int i = 0; i < 4; ++i) {
      sum[i] += __shfl_xor(sum[i], m, 64);
      sq[i]  += __shfl_xor(sq[i],  m, 64);
    }
  }
  f32x4 c4 = sum * sum - sq;
  float cross = 0.5f * (c4[0] + c4[1] + c4[2] + c4[3]);   // this t4's 4 dims
  cross += __shfl_xor(cross, 1, 64);
  cross += __shfl_xor(cross, 2, 64);
  lin += __shfl_xor(lin, 1, 64);
  lin += __shfl_xor(lin, 2, 64);
  lin += __shfl_xor(lin, 4, 64);
  lin += __shfl_xor(lin, 8, 64);
  lin += __shfl_xor(lin, 16, 64);
  if (t == 0) fmw[row] = cross + lin + bias[0];
}

// ---------------------------------------------------------------------------
// Per-wave weight staging: wave w DMAs ONLY its own n-range [w*112, w*112+112)
// into its private quarter of the chunk buffer -> no cross-wave wbuf deps ->
// no barriers in the K-loop. 16B granules XOR-swizzled on the *source* side
// (slot s holds granule g = (s&3) ^ ((n_local>>1)&3)) so b64 reads spread
// across ~16+ banks instead of 8 (row stride 64B is pathological unswizzled).
// ---------------------------------------------------------------------------
__device__ __forceinline__ void stage_w_chunk(
    const unsigned char* __restrict__ Wt, int kt, unsigned char* wb,
    int wave, int lane) {
  const unsigned char* wrow = Wt + (size_t)(wave * 112) * NP + kt * 64;
  unsigned char* lbase = wb + wave * WQTR;
#pragma unroll
  for (int i = 0; i < 7; ++i) {
    int s = i * 64 + lane;
    int nl = s >> 2;
    int g = (s & 3) ^ ((nl >> 1) & 3);
    const unsigned char* gp = wrow + (size_t)nl * NP + g * 16;
    unsigned char* lp = lbase + (size_t)(i * 64) * 16;   // wave-uniform + lane*16
    __builtin_amdgcn_global_load_lds(
        (const __attribute__((address_space(1))) unsigned int*)gp,
        (__attribute__((address_space(3))) unsigned int*)lp, 16, 0, 0);
  }
}

// ---------------------------------------------------------------------------
// gemm_all: 64 batch rows/block. act reg-staged from ws into padded-456 LDS;
// 3 fp8 MFMA layers in place; weight chunks double-buffered, K-loop
// barrier-free with per-wave s_waitcnt vmcnt gating; layer-2 epilogue fuses
// h2 . W_out; out = fm + dot.
// ---------------------------------------------------------------------------
__global__ __launch_bounds__(256, 1) void gemm_all(
    const unsigned char* __restrict__ W0t, const unsigned char* __restrict__ W1t,
    const unsigned char* __restrict__ W2t,
    const float* __restrict__ b0p, const float* __restrict__ b1p,
    const float* __restrict__ b2p, const float* __restrict__ woutp,
    const unsigned char* __restrict__ actw, const float* __restrict__ fmw,
    float* __restrict__ out) {
  extern __shared__ char smem[];
  unsigned char* act  = (unsigned char*)(smem + ACT_OFF);   // [64][456] fp8
  unsigned char* wbuf = (unsigned char*)(smem + WBUF_OFF);  // 2 x [4 waves][112][64]
  float* dotv = (float*)(smem + DOT_OFF);                   // [64]

  const int tid  = threadIdx.x;
  const int wave = tid >> 6;
  const int lane = tid & 63;
  const int quad = lane >> 4;
  const int l16  = lane & 15;
  const int r0   = blockIdx.x * MT;

  // kick off layer-0 chunk-0 DMA immediately (overlaps act staging)
  stage_w_chunk(W0t, 0, wbuf, wave, lane);

  if (tid < MT) dotv[tid] = 0.f;

  // stage act [64][448] -> LDS [64][456] in 8B granules (coalesced reads)
#pragma unroll
  for (int it = 0; it < 14; ++it) {
    int c = it * 256 + tid;        // 0..3583
    int row = c / 56;
    int off = c - row * 56;
    long long v = *(const long long*)(actw + (size_t)(r0 + row) * NP + off * 8);
    *(long long*)(act + row * ASTR + off * 8) = v;
  }

  __syncthreads();  // act resident; chunk-0 DMA also complete before K use

  const unsigned char* Wl[3] = {W0t, W1t, W2t};

  for (int layer = 0; layer < 3; ++layer) {
    const unsigned char* Wt = Wl[layer];
    const unsigned char* wq = wbuf + wave * WQTR;   // this wave's quarter
    f32x4 acc[4][7] = {};

    // barrier-free K-loop: double-buffered chunks, per-wave vmcnt gating
    for (int kt = 0; kt < 7; ++kt) {
      if (kt < 6) {
        stage_w_chunk(Wt, kt + 1, wbuf + ((kt + 1) & 1) * WCHB, wave, lane);
        __builtin_amdgcn_s_waitcnt(WAIT_VM7);  // chunk kt resident; kt+1 in flight
      } else {
        __builtin_amdgcn_s_waitcnt(WAIT_VM0);  // last chunk of layer
      }
      __builtin_amdgcn_sched_barrier(0);       // keep ds_reads below the wait
      const unsigned char* wb = wq + (kt & 1) * WCHB;

#pragma unroll
      for (int h = 0; h < 2; ++h) {
        long long av[4];
#pragma unroll
        for (int mt = 0; mt < 4; ++mt)
          av[mt] = *(const long long*)(act + (mt * 16 + l16) * ASTR + kt * 64 + h * 32 + quad * 8);
#pragma unroll
        for (int nt = 0; nt < 7; ++nt) {
          int nl = nt * 16 + l16;
          int sw = (2 * h + (quad >> 1)) ^ ((nl >> 1) & 3);
          long long bv = *(const long long*)(wb + nl * 64 + sw * 16 + (quad & 1) * 8);
#pragma unroll
          for (int mt = 0; mt < 4; ++mt)
            acc[mt][nt] = __builtin_amdgcn_mfma_f32_16x16x32_fp8_fp8(av[mt], bv, acc[mt][nt], 0, 0, 0);
        }
      }
    }

    // prefetch next layer's chunk 0 before the barrier (drained there; resident
    // for kt=0 of the next layer)
    if (layer < 2) stage_w_chunk(Wl[layer + 1], 0, wbuf, wave, lane);

    __syncthreads();  // all waves done reading act for this layer

    if (layer < 2) {
      const float fs = (layer == 0) ? SC_F0 : SC_F1;
      const float* bl = (layer == 0) ? b0p : b1p;
#pragma unroll
      for (int nt = 0; nt < 7; ++nt) {
        int col = wave * 112 + nt * 16 + l16;
        float bz = bl[col];
#pragma unroll
        for (int mt = 0; mt < 4; ++mt) {
#pragma unroll
          for (int r = 0; r < 4; ++r) {
            float v = acc[mt][nt][r] * fs + bz;
            v = v > 0.f ? v : 0.f;
            act[(mt * 16 + quad * 4 + r) * ASTR + col] = f2fp8(v);
          }
        }
      }
    } else {
      float wsum[4][4] = {};
#pragma unroll
      for (int nt = 0; nt < 7; ++nt) {
        int col = wave * 112 + nt * 16 + l16;
        float bz = b2p[col];
        float wv = woutp[col];
#pragma unroll
        for (int mt = 0; mt < 4; ++mt) {
#pragma unroll
          for (int r = 0; r < 4; ++r) {
            float v = acc[mt][nt][r] * SC_G + bz;
            v = v > 0.f ? v : 0.f;
            wsum[mt][r] += v * wv;
          }
        }
      }
#pragma unroll
      for (int mt = 0; mt < 4; ++mt) {
#pragma unroll
        for (int r = 0; r < 4; ++r) {
          float s = wsum[mt][r];
          s += __shfl_xor(s, 1, 64);
          s += __shfl_xor(s, 2, 64);
          s += __shfl_xor(s, 4, 64);
          s += __shfl_xor(s, 8, 64);
          if (l16 == 0) atomicAdd(&dotv[mt * 16 + quad * 4 + r], s);
        }
      }
    }
    __syncthreads();  // epilogue writes visible before next layer / final read
  }

  if (tid < MT) out[r0 + tid] = fmw[r0 + tid] + dotv[tid];
}

// ---------------------------------------------------------------------------
extern "C" void kernel_launch(void* const* d_in, const int* in_sizes, int n_in,
                              void* d_out, int out_size, void* d_ws, size_t ws_size,
                              hipStream_t stream) {
  const int*   Xs   = (const int*)d_in[0];
  const float* Xd   = (const float*)d_in[1];
  const float* emb1 = (const float*)d_in[2];
  const float* emb2 = (const float*)d_in[3];
  const float* linw = (const float*)d_in[4];
  const float* bias = (const float*)d_in[5];
  const float* W0   = (const float*)d_in[6];
  const float* b0   = (const float*)d_in[7];
  const float* W1   = (const float*)d_in[8];
  const float* b1   = (const float*)d_in[9];
  const float* W2   = (const float*)d_in[10];
  const float* b2   = (const float*)d_in[11];
  const float* Wout = (const float*)d_in[12];
  float* out = (float*)d_out;

  char* ws = (char*)d_ws;
  const size_t WSZ = (size_t)NP * NP;   // 200704 bytes per fp8 weight
  unsigned char* W0t = (unsigned char*)(ws);
  unsigned char* W1t = (unsigned char*)(ws + WSZ);
  unsigned char* W2t = (unsigned char*)(ws + 2 * WSZ);
  float* b0p   = (float*)(ws + 3 * WSZ);
  float* b1p   = (float*)(ws + 3 * WSZ + 1792);
  float* b2p   = (float*)(ws + 3 * WSZ + 2 * 1792);
  float* woutp = (float*)(ws + 3 * WSZ + 3 * 1792);
  unsigned char* actw = (unsigned char*)(ws + 3 * WSZ + 4 * 1792);   // [16384][448]
  float* fmw = (float*)(ws + 3 * WSZ + 4 * 1792 + (size_t)B_ * NP);  // [16384]

  (void)hipFuncSetAttribute((const void*)gemm_all,
                            hipFuncAttributeMaxDynamicSharedMemorySize, LDSB);

  gather_prep<<<148 + B_ / 8, 256, PREP_LDS, stream>>>(
      Xs, Xd, emb1, emb2, linw, bias, W0, b0, W1, b1, W2, b2, Wout,
      W0t, W1t, W2t, b0p, b1p, b2p, woutp, actw, fmw);

  gemm_all<<<B_ / MT, 256, LDSB, stream>>>(
      W0t, W1t, W2t, b0p, b1p, b2p, woutp, actw, fmw, out);
}